// Round 13
// baseline (596.007 us; speedup 1.0000x reference)
//
#include <hip/hip_runtime.h>
#include <math.h>

#define N_NODES 100000
#define N_EDGES 3200000
#define D_FEAT 256
#define GC_HID 20
#define DEC_HID 40
#define Z_DIM 32

#define EPB 2048          // edges per sort block
#define NBLK 1563         // ceil(3.2M / 2048)
#define SB 392            // receiver buckets of 256 nodes (392*256 = 100352)
#define SBSH 8
#define S2CAP 12288       // per-bucket record cap
#define GCB 128           // nodes per block for k_gc1 (782 blocks)
#define ENB 256           // nodes per block for k_encf (391 blocks, 8 waves)
#define NXCD 8

// ---------------- ws layout (bytes) ----------------
// h_pre  @ 0           8,000,000   (dead after 2nd gather; dbuf overlays @0)
// agg    @ 8,000,000   8,000,000   (dead after k_encf)
// dbuf   @ 0          16,000,000   (k_decd output; overlays h_pre+agg)
// grec   @16,000,000  12,804,096   (bucket-sorted records; dead after 2nd gather)
// zone Z @28,804,096:
//   rec_r  @28,804,096 12,804,096  (dead after k_gscat)
//   srow_r @41,608,192  1,228,518  (dead after k_gscat)
//   pref_t @42,836,720  2,450,784  (dead after k_gscat)
//   zbuf   @28,804,096 12,800,000  (k_z output, after gscat)
// row_ptr @45,287,504    400,004
// gtot    @45,687,508      1,568
// gbase   @45,689,076      1,572
// deg_priv@45,690,648  3,200,000   (8 XCD-private histograms)
// rs_s    @48,890,648    400,000   end = 49,290,648

// local counting sort by receiver bucket + XCD-private deg_s histogram
__global__ __launch_bounds__(512) void k_sort(const int* __restrict__ snd,
                                              const int* __restrict__ rcv,
                                              unsigned* __restrict__ rec_r,
                                              unsigned short* __restrict__ srow_r,
                                              unsigned* __restrict__ deg_priv) {
    __shared__ int es[EPB], er[EPB];
    __shared__ unsigned scan[SB + 1];
    __shared__ unsigned cur[SB];
    __shared__ unsigned sorted[EPB];
    int b = blockIdx.x, t = threadIdx.x;
    // blocks dispatch round-robin across the 8 XCDs: b&7 selects an
    // XCD-private histogram copy -> atomic lines never migrate between
    // XCD L2s (correct under any mapping; fast under round-robin).
    unsigned* deg = deg_priv + (size_t)(b & (NXCD - 1)) * N_NODES;
    int base = b * EPB;
    int cnt = min(EPB, N_EDGES - base);
    for (int i = t; i < cnt; i += 512) { es[i] = snd[base + i]; er[i] = rcv[base + i]; }
    for (int i = t; i < SB + 1; i += 512) scan[i] = 0u;
    __syncthreads();
    for (int i = t; i < cnt; i += 512) {
        atomicAdd(&scan[(er[i] >> SBSH) + 1], 1u);
        atomicAdd(&deg[es[i]], 1u);
    }
    __syncthreads();
    for (int off = 1; off < SB + 1; off <<= 1) {
        unsigned v = (t >= off && t < SB + 1) ? scan[t - off] : 0u;
        __syncthreads();
        if (t < SB + 1) scan[t] += v;
        __syncthreads();
    }
    for (int i = t; i < SB + 1; i += 512) srow_r[(size_t)b * (SB + 1) + i] = (unsigned short)scan[i];
    if (t < SB) cur[t] = scan[t];
    __syncthreads();
    for (int i = t; i < cnt; i += 512) {
        int r = er[i];
        unsigned pos = atomicAdd(&cur[r >> SBSH], 1u);
        sorted[pos] = ((unsigned)(r & 255) << 17) | (unsigned)es[i];
    }
    __syncthreads();
    for (int i = t; i < cnt; i += 512) rec_r[(size_t)base + i] = sorted[i];
}

// reduce the 8 XCD-private histograms -> rs_s = rsqrt(max(deg,1))
__global__ __launch_bounds__(256) void k_rs(const unsigned* __restrict__ deg_priv,
                                            float* __restrict__ rs_s) {
    int i = blockIdx.x * 256 + threadIdx.x;
    if (i >= N_NODES) return;
    unsigned s = 0;
#pragma unroll
    for (int x = 0; x < NXCD; ++x) s += deg_priv[(size_t)x * N_NODES + i];
    rs_s[i] = rsqrtf(fmaxf((float)s, 1.0f));
}

// per-bucket prefix over block segments: pref_t[s][k], totals gtot[s]
__global__ __launch_bounds__(256) void k_scanB(const unsigned short* __restrict__ srow_r,
                                               unsigned* __restrict__ pref_t,
                                               unsigned* __restrict__ gtot) {
    __shared__ unsigned buf[256];
    int s = blockIdx.x, t = threadIdx.x;
    unsigned run = 0;
    for (int k0 = 0; k0 < NBLK; k0 += 256) {
        int k = k0 + t;
        unsigned v = 0;
        if (k < NBLK) {
            const unsigned short* row = srow_r + (size_t)k * (SB + 1);
            v = (unsigned)row[s + 1] - (unsigned)row[s];
        }
        buf[t] = v;
        __syncthreads();
        for (int off = 1; off < 256; off <<= 1) {
            unsigned x = (t >= off) ? buf[t - off] : 0u;
            __syncthreads();
            buf[t] += x;
            __syncthreads();
        }
        if (k < NBLK) pref_t[(size_t)s * NBLK + k] = run + (buf[t] - v);
        unsigned tot = buf[255];
        __syncthreads();
        run += tot;
    }
    if (t == 0) gtot[s] = run;
}

// exclusive scan of bucket totals -> gbase[SB+1]
__global__ __launch_bounds__(512) void k_scanG(const unsigned* __restrict__ gtot,
                                               unsigned* __restrict__ gbase) {
    __shared__ unsigned buf[SB];
    int t = threadIdx.x;
    if (t < SB) buf[t] = gtot[t];
    __syncthreads();
    for (int off = 1; off < SB; off <<= 1) {
        unsigned x = (t >= off && t < SB) ? buf[t - off] : 0u;
        __syncthreads();
        if (t < SB) buf[t] += x;
        __syncthreads();
    }
    if (t < SB) gbase[t + 1] = buf[t];
    if (t == 0) gbase[0] = 0u;
}

// scatter block-sorted records to global bucket-sorted order
__global__ __launch_bounds__(256) void k_gscat(const unsigned* __restrict__ rec_r,
                                               const unsigned short* __restrict__ srow_r,
                                               const unsigned* __restrict__ pref_t,
                                               const unsigned* __restrict__ gbase,
                                               unsigned* __restrict__ grec) {
    __shared__ unsigned recs[EPB];
    __shared__ unsigned short srow[SB + 1];
    int b = blockIdx.x, t = threadIdx.x;
    int base = b * EPB;
    int cnt = min(EPB, N_EDGES - base);
    for (int i = t; i < cnt; i += 256) recs[i] = rec_r[(size_t)base + i];
    for (int i = t; i < SB + 1; i += 256) srow[i] = srow_r[(size_t)b * (SB + 1) + i];
    __syncthreads();
    for (int s = t; s < SB; s += 256) {
        unsigned lo = srow[s], hi = srow[s + 1];
        if (lo == hi) continue;
        unsigned dst = gbase[s] + pref_t[(size_t)s * NBLK + b];
        for (unsigned i = lo; i < hi; ++i) grec[dst + (i - lo)] = recs[i];
    }
}

// within-bucket counting sort by local receiver (in-place) + CSR row_ptr
__global__ __launch_bounds__(256) void k_sort2(unsigned* __restrict__ grec,
                                               const unsigned* __restrict__ gbase,
                                               unsigned* __restrict__ row_ptr) {
    __shared__ unsigned recs[S2CAP];     // 48 KB
    __shared__ unsigned hist[256];
    __shared__ unsigned scan[256];
    __shared__ unsigned cur[256];
    int s = blockIdx.x, t = threadIdx.x;
    unsigned lo = gbase[s], hi = gbase[s + 1];
    unsigned cnt = min(hi - lo, (unsigned)S2CAP);
    for (unsigned i = t; i < cnt; i += 256) recs[i] = grec[lo + i];
    hist[t] = 0u;
    __syncthreads();
    for (unsigned i = t; i < cnt; i += 256) atomicAdd(&hist[recs[i] >> 17], 1u);
    __syncthreads();
    unsigned v = hist[t];
    scan[t] = v;
    __syncthreads();
    for (int off = 1; off < 256; off <<= 1) {
        unsigned x = (t >= off) ? scan[t - off] : 0u;
        __syncthreads();
        scan[t] += x;
        __syncthreads();
    }
    unsigned excl = scan[t] - v;   // exclusive prefix of bin t
    {
        int n = (s << SBSH) + t;
        if (n <= N_NODES) row_ptr[n] = lo + excl;
    }
    cur[t] = excl;
    __syncthreads();
    for (unsigned i = t; i < cnt; i += 256) {
        unsigned rec = recs[i];
        unsigned pos = atomicAdd(&cur[rec >> 17], 1u);
        grec[lo + pos] = rec & 0x1FFFFu;   // sender only
    }
}

// pure CSR gather: 5 lanes per node, one float4 each; zero atomics.
__global__ __launch_bounds__(320) void k_gather(const unsigned* __restrict__ row_ptr,
                                                const unsigned* __restrict__ grec,
                                                const float* __restrict__ src,
                                                float* __restrict__ dst) {
    int gid = blockIdx.x * 320 + threadIdx.x;
    int node = gid / 5, q = gid % 5;
    if (node >= N_NODES) return;
    unsigned lo = row_ptr[node], hi = row_ptr[node + 1];
    float4 acc = make_float4(0.f, 0.f, 0.f, 0.f);
    float4 acc2 = make_float4(0.f, 0.f, 0.f, 0.f);
    unsigned e = lo;
    for (; e + 2 <= hi; e += 2) {
        unsigned sa = grec[e], sb = grec[e + 1];
        float4 v1 = ((const float4*)src)[sa * 5 + q];
        float4 v2 = ((const float4*)src)[sb * 5 + q];
        acc.x += v1.x; acc.y += v1.y; acc.z += v1.z; acc.w += v1.w;
        acc2.x += v2.x; acc2.y += v2.y; acc2.z += v2.z; acc2.w += v2.w;
    }
    if (e < hi) {
        unsigned sa = grec[e];
        float4 v1 = ((const float4*)src)[sa * 5 + q];
        acc.x += v1.x; acc.y += v1.y; acc.z += v1.z; acc.w += v1.w;
    }
    acc.x += acc2.x; acc.y += acc2.y; acc.z += acc2.z; acc.w += acc2.w;
    float sc = rsqrtf(fmaxf((float)(hi - lo), 1.0f));
    acc.x *= sc; acc.y *= sc; acc.z *= sc; acc.w *= sc;
    ((float4*)dst)[node * 5 + q] = acc;
}

// GC layer 1: thread-per-node, nodes staged through LDS in coalesced
// 16-float K-chunks (pad-17 rows -> conflict-free b32 reads), weights s_load.
__global__ __launch_bounds__(128) void k_gc1(const float* __restrict__ nodes,
                                             const float* __restrict__ W1,
                                             const float* __restrict__ b1,
                                             const float* __restrict__ rs_s,
                                             float* __restrict__ h_pre) {
    __shared__ float tile[GCB * 17];
    int t = threadIdx.x;
    int n0 = blockIdx.x * GCB;
    int node = n0 + t;
    float acc[GC_HID];
#pragma unroll
    for (int j = 0; j < GC_HID; ++j) acc[j] = b1[j];

    int r = t >> 2, c4 = t & 3;
    for (int ch = 0; ch < 16; ++ch) {
        __syncthreads();
#pragma unroll
        for (int i = 0; i < 4; ++i) {
            int row = r + i * 32;
            int gn = n0 + row;
            float4 v = (gn < N_NODES)
                ? ((const float4*)nodes)[(size_t)gn * 64 + ch * 4 + c4]
                : make_float4(0.f, 0.f, 0.f, 0.f);
            float* dst = &tile[row * 17 + c4 * 4];
            dst[0] = v.x; dst[1] = v.y; dst[2] = v.z; dst[3] = v.w;
        }
        __syncthreads();
        const float* wb = W1 + ch * 16 * GC_HID;
#pragma unroll
        for (int kk = 0; kk < 16; ++kk) {
            float x = tile[t * 17 + kk];
            const float* wr = wb + kk * GC_HID;
#pragma unroll
            for (int j = 0; j < GC_HID; ++j) acc[j] = fmaf(x, wr[j], acc[j]);
        }
    }
    if (node >= N_NODES) return;
    float mx = -1e30f;
#pragma unroll
    for (int j = 0; j < GC_HID; ++j) {
        acc[j] = fmaxf(acc[j], 0.0f);
        mx = fmaxf(mx, acc[j]);
    }
    float s = 0.0f;
#pragma unroll
    for (int j = 0; j < GC_HID; ++j) {
        acc[j] = __expf(acc[j] - mx);
        s += acc[j];
    }
    float inv = rs_s[node] / s;
#pragma unroll
    for (int j = 0; j < GC_HID; ++j) acc[j] *= inv;
    float4* o = (float4*)&h_pre[(size_t)node * GC_HID];
    o[0] = make_float4(acc[0],  acc[1],  acc[2],  acc[3]);
    o[1] = make_float4(acc[4],  acc[5],  acc[6],  acc[7]);
    o[2] = make_float4(acc[8],  acc[9],  acc[10], acc[11]);
    o[3] = make_float4(acc[12], acc[13], acc[14], acc[15]);
    o[4] = make_float4(acc[16], acc[17], acc[18], acc[19]);
}

// GC layer 2 transform: h2_pre = softmax(relu(h1@W2+b2)) * rs_s
__global__ __launch_bounds__(256) void k_gc2(const float* __restrict__ h1in,
                                             const float* __restrict__ W2,
                                             const float* __restrict__ b2,
                                             const float* __restrict__ rs_s,
                                             float* __restrict__ h2_pre) {
    __shared__ float Wsh[GC_HID * GC_HID];
    __shared__ float bsh[GC_HID];
    int tid = threadIdx.x;
    if (tid < GC_HID * GC_HID) Wsh[tid] = W2[tid];
    if (tid < GC_HID) bsh[tid] = b2[tid];
    __syncthreads();
    int node = blockIdx.x * 256 + tid;
    if (node >= N_NODES) return;
    const float4* ap = (const float4*)&h1in[node * GC_HID];
    float4 a0 = ap[0], a1 = ap[1], a2 = ap[2], a3 = ap[3], a4 = ap[4];
    float h1[GC_HID] = {a0.x,a0.y,a0.z,a0.w, a1.x,a1.y,a1.z,a1.w,
                        a2.x,a2.y,a2.z,a2.w, a3.x,a3.y,a3.z,a3.w,
                        a4.x,a4.y,a4.z,a4.w};
    float t[GC_HID];
#pragma unroll
    for (int j = 0; j < GC_HID; ++j) t[j] = bsh[j];
#pragma unroll
    for (int i = 0; i < GC_HID; ++i) {
        float x = h1[i];
#pragma unroll
        for (int j = 0; j < GC_HID; ++j) t[j] = fmaf(x, Wsh[i * GC_HID + j], t[j]);
    }
    float mx = -1e30f;
#pragma unroll
    for (int j = 0; j < GC_HID; ++j) { t[j] = fmaxf(t[j], 0.0f); mx = fmaxf(mx, t[j]); }
    float s = 0.0f;
#pragma unroll
    for (int j = 0; j < GC_HID; ++j) { t[j] = __expf(t[j] - mx); s += t[j]; }
    float inv = rs_s[node] / s;
#pragma unroll
    for (int j = 0; j < GC_HID; ++j) t[j] *= inv;
    float4* o = (float4*)&h2_pre[node * GC_HID];
    o[0] = make_float4(t[0],  t[1],  t[2],  t[3]);
    o[1] = make_float4(t[4],  t[5],  t[6],  t[7]);
    o[2] = make_float4(t[8],  t[9],  t[10], t[11]);
    o[3] = make_float4(t[12], t[13], t[14], t[15]);
    o[4] = make_float4(t[16], t[17], t[18], t[19]);
}

// fused encoder head, 8 waves/block: wave = (half<<2)|node_group.
// half forced wave-uniform via readfirstlane -> weights stay s_load.
__global__ __launch_bounds__(512) void k_encf(const float* __restrict__ h2in,
                                              const float* __restrict__ nodes,
                                              const float* __restrict__ Wmu,
                                              const float* __restrict__ bmu,
                                              const float* __restrict__ Wls,
                                              const float* __restrict__ bls,
                                              float* __restrict__ mu_out,
                                              float* __restrict__ ls_out) {
    __shared__ float tile[ENB * 17];   // 17,408 B
    int t = threadIdx.x;
    int wave = t >> 6, lane = t & 63;
    int ng = wave & 3;                 // node group within block
    int half = __builtin_amdgcn_readfirstlane(wave >> 2);  // 0 = mu, 1 = ls
    int n0 = blockIdx.x * ENB;
    int lrow = ng * 64 + lane;
    int node = n0 + lrow;
    const float* W  = half ? Wls : Wmu;
    const float* bb = half ? bls : bmu;
    float* out      = half ? ls_out : mu_out;

    float acc[Z_DIM];
#pragma unroll
    for (int j = 0; j < Z_DIM; ++j) acc[j] = bb[j];

    if (node < N_NODES) {
        const float4* hp = (const float4*)(h2in + (size_t)node * GC_HID);
#pragma unroll
        for (int v = 0; v < 5; ++v) {
            float4 hh = hp[v];
#pragma unroll
            for (int c = 0; c < 4; ++c) {
                float x = (c == 0) ? hh.x : (c == 1) ? hh.y : (c == 2) ? hh.z : hh.w;
                const float* wr = W + (v * 4 + c) * Z_DIM;
#pragma unroll
                for (int j = 0; j < Z_DIM; ++j) acc[j] = fmaf(x, wr[j], acc[j]);
            }
        }
    }
    for (int ch = 0; ch < 16; ++ch) {
        __syncthreads();
#pragma unroll
        for (int rep = 0; rep < 2; ++rep) {
            int idx = rep * 512 + t;       // 0..1023
            int row = idx >> 2, k4 = idx & 3;
            int gn = n0 + row;
            float4 v = (gn < N_NODES)
                ? ((const float4*)nodes)[(size_t)gn * 64 + ch * 4 + k4]
                : make_float4(0.f, 0.f, 0.f, 0.f);
            float* dst = &tile[row * 17 + k4 * 4];
            dst[0] = v.x; dst[1] = v.y; dst[2] = v.z; dst[3] = v.w;
        }
        __syncthreads();
#pragma unroll
        for (int kk = 0; kk < 16; ++kk) {
            float x = tile[lrow * 17 + kk];
            const float* wr = W + (GC_HID + ch * 16 + kk) * Z_DIM;
#pragma unroll
            for (int j = 0; j < Z_DIM; ++j) acc[j] = fmaf(x, wr[j], acc[j]);
        }
    }
    if (node >= N_NODES) return;
    float4* op = (float4*)(out + (size_t)node * Z_DIM);
#pragma unroll
    for (int v = 0; v < Z_DIM / 4; ++v)
        op[v] = make_float4(acc[4*v], acc[4*v+1], acc[4*v+2], acc[4*v+3]);
}

// reparameterization: z = mu + (1e-4 + exp(0.5*ls)) * eps
__global__ __launch_bounds__(256) void k_z(const float* __restrict__ mu,
                                           const float* __restrict__ ls,
                                           const float* __restrict__ eps,
                                           float* __restrict__ z) {
    int i = blockIdx.x * 256 + threadIdx.x;
    if (i >= N_NODES * Z_DIM / 4) return;
    float4 m = ((const float4*)mu)[i];
    float4 l = ((const float4*)ls)[i];
    float4 e = ((const float4*)eps)[i];
    float4 zz;
    zz.x = m.x + (1e-4f + __expf(0.5f * l.x)) * e.x;
    zz.y = m.y + (1e-4f + __expf(0.5f * l.y)) * e.y;
    zz.z = m.z + (1e-4f + __expf(0.5f * l.z)) * e.z;
    zz.w = m.w + (1e-4f + __expf(0.5f * l.w)) * e.w;
    ((float4*)z)[i] = zz;
}

// decoder stage 1: d = relu(z@Wd1+bd1), thread per node (weights uniform)
__global__ __launch_bounds__(256) void k_decd(const float* __restrict__ z,
                                              const float* __restrict__ Wd1,
                                              const float* __restrict__ bd1,
                                              float* __restrict__ dbuf) {
    int node = blockIdx.x * 256 + threadIdx.x;
    if (node >= N_NODES) return;
    float d[DEC_HID];
#pragma unroll
    for (int j = 0; j < DEC_HID; ++j) d[j] = bd1[j];
    const float4* zp = (const float4*)(z + (size_t)node * Z_DIM);
#pragma unroll
    for (int v = 0; v < Z_DIM / 4; ++v) {
        float4 zz = zp[v];
#pragma unroll
        for (int c = 0; c < 4; ++c) {
            float x = (c == 0) ? zz.x : (c == 1) ? zz.y : (c == 2) ? zz.z : zz.w;
            const float* wr = Wd1 + (v * 4 + c) * DEC_HID;
#pragma unroll
            for (int j = 0; j < DEC_HID; ++j) d[j] = fmaf(x, wr[j], d[j]);
        }
    }
    float4* op = (float4*)(dbuf + (size_t)node * DEC_HID);
#pragma unroll
    for (int v = 0; v < DEC_HID / 4; ++v)
        op[v] = make_float4(fmaxf(d[4*v], 0.f), fmaxf(d[4*v+1], 0.f),
                            fmaxf(d[4*v+2], 0.f), fmaxf(d[4*v+3], 0.f));
}

// decoder stage 2: chunk id forced wave-uniform via readfirstlane; lane = node.
__global__ __launch_bounds__(256) void k_decx(const float* __restrict__ dbuf,
                                              const float* __restrict__ Wd2,
                                              const float* __restrict__ bd2,
                                              float* __restrict__ X) {
    int lane = threadIdx.x & 63;
    int wv   = threadIdx.x >> 6;             // 0..3
    int ch   = __builtin_amdgcn_readfirstlane(((blockIdx.x & 1) << 2) | wv);
    int node = (blockIdx.x >> 1) * 64 + lane;
    if (node >= N_NODES) return;
    int co = ch << 5;
    float o[32];
#pragma unroll
    for (int j = 0; j < 32; ++j) o[j] = bd2[co + j];
    const float4* dp = (const float4*)(dbuf + (size_t)node * DEC_HID);
#pragma unroll
    for (int v = 0; v < DEC_HID / 4; ++v) {
        float4 dd = dp[v];
#pragma unroll
        for (int c = 0; c < 4; ++c) {
            float x = (c == 0) ? dd.x : (c == 1) ? dd.y : (c == 2) ? dd.z : dd.w;
            const float* wr = Wd2 + (v * 4 + c) * D_FEAT + co;
#pragma unroll
            for (int j = 0; j < 32; ++j) o[j] = fmaf(x, wr[j], o[j]);
        }
    }
    float4* xp = (float4*)(X + (size_t)node * D_FEAT + co);
#pragma unroll
    for (int v = 0; v < 8; ++v)
        xp[v] = make_float4(o[4*v], o[4*v+1], o[4*v+2], o[4*v+3]);
}

extern "C" void kernel_launch(void* const* d_in, const int* in_sizes, int n_in,
                              void* d_out, int out_size, void* d_ws, size_t ws_size,
                              hipStream_t stream) {
    const float* nodes = (const float*)d_in[0];
    const int*   snd   = (const int*)d_in[1];
    const int*   rcv   = (const int*)d_in[2];
    const float* eps   = (const float*)d_in[3];
    const float* W1    = (const float*)d_in[4];
    const float* b1    = (const float*)d_in[5];
    const float* W2    = (const float*)d_in[6];
    const float* b2    = (const float*)d_in[7];
    const float* Wmu   = (const float*)d_in[8];
    const float* bmu   = (const float*)d_in[9];
    const float* Wls   = (const float*)d_in[10];
    const float* bls   = (const float*)d_in[11];
    const float* Wd1   = (const float*)d_in[12];
    const float* bd1   = (const float*)d_in[13];
    const float* Wd2   = (const float*)d_in[14];
    const float* bd2   = (const float*)d_in[15];

    char* ws = (char*)d_ws;
    float*          h_pre    = (float*)(ws);
    float*          agg      = (float*)(ws + 8000000);
    float*          dbuf     = (float*)(ws);              // overlays h_pre+agg (dead)
    unsigned*       grec     = (unsigned*)(ws + 16000000);
    unsigned*       rec_r    = (unsigned*)(ws + 28804096);
    unsigned short* srow_r   = (unsigned short*)(ws + 41608192);
    unsigned*       pref_t   = (unsigned*)(ws + 42836720);
    float*          zbuf     = (float*)(ws + 28804096);   // reuses rec_r zone after gscat
    unsigned*       row_ptr  = (unsigned*)(ws + 45287504);
    unsigned*       gtot     = (unsigned*)(ws + 45687508);
    unsigned*       gbase    = (unsigned*)(ws + 45689076);
    unsigned*       deg_priv = (unsigned*)(ws + 45690648);
    float*          rs_s     = (float*)(ws + 48890648);

    float* X      = (float*)d_out;
    float* mu_out = X + (size_t)N_NODES * D_FEAT;
    float* ls_out = mu_out + (size_t)N_NODES * Z_DIM;

    hipMemsetAsync(deg_priv, 0, NXCD * N_NODES * 4, stream);

    k_sort<<<NBLK, 512, 0, stream>>>(snd, rcv, rec_r, srow_r, deg_priv);
    k_rs<<<391, 256, 0, stream>>>(deg_priv, rs_s);
    k_scanB<<<SB, 256, 0, stream>>>(srow_r, pref_t, gtot);
    k_scanG<<<1, 512, 0, stream>>>(gtot, gbase);
    k_gscat<<<NBLK, 256, 0, stream>>>(rec_r, srow_r, pref_t, gbase, grec);
    k_sort2<<<SB, 256, 0, stream>>>(grec, gbase, row_ptr);

    k_gc1<<<782, 128, 0, stream>>>(nodes, W1, b1, rs_s, h_pre);
    k_gather<<<1563, 320, 0, stream>>>(row_ptr, grec, h_pre, agg);
    k_gc2<<<391, 256, 0, stream>>>(agg, W2, b2, rs_s, h_pre);
    k_gather<<<1563, 320, 0, stream>>>(row_ptr, grec, h_pre, agg);

    k_encf<<<391, 512, 0, stream>>>(agg, nodes, Wmu, bmu, Wls, bls,
                                    mu_out, ls_out);
    k_z<<<3125, 256, 0, stream>>>(mu_out, ls_out, eps, zbuf);
    k_decd<<<391, 256, 0, stream>>>(zbuf, Wd1, bd1, dbuf);
    k_decx<<<3126, 256, 0, stream>>>(dbuf, Wd2, bd2, X);
}

// Round 14
// 499.758 us; speedup vs baseline: 1.1926x; 1.1926x over previous
//
#include <hip/hip_runtime.h>
#include <math.h>

#define N_NODES 100000
#define N_EDGES 3200000
#define D_FEAT 256
#define GC_HID 20
#define DEC_HID 40
#define Z_DIM 32

#define EPB 2048          // edges per sort block
#define NBLK 1563         // ceil(3.2M / 2048)
#define SB 392            // node buckets of 256 (392*256 = 100352)
#define SBSH 8
#define S2CAP 12288       // per-bucket record cap
#define GCB 128           // nodes per block for k_gc1 (782 blocks)
#define ENB 256           // nodes per block for k_encf (391 blocks, 8 waves)

// ---------------- ws layout (bytes) ----------------
// h_pre  @ 0           8,000,000   (dead after 2nd gather; dbuf overlays @0)
// agg    @ 8,000,000   8,000,000   (dead after k_encf)
// dbuf   @ 0          16,000,000   (k_decd output; overlays h_pre+agg)
// grec   @16,000,000  12,804,096   (bucket-sorted records; dead after 2nd gather)
// zone Z @28,804,096:
//   rec_r  @28,804,096 12,804,096  (dead after k_gscat)
//   srow_r @41,608,192  1,228,518  (dead after k_gscat)
//   pref_t @42,836,720  2,450,784  (dead after k_gscat)
//   zbuf   @28,804,096 12,800,000  (k_z output, after gscat)
// row_ptr @45,287,504    400,004
// gtot    @45,687,508      1,568
// gbase   @45,689,076      1,572
// rs_s    @45,690,648    400,000
// rec_s   @46,090,648  3,201,024   (u8 sender-sorted stream)
// srow_s  @49,291,672  1,228,518   end = 50,520,190

// dual block-local counting sort (receiver u32 + sender u8 streams).
// ZERO global atomics: all histograms/cursors live in LDS; all global
// writes are coalesced block-owned regions (memory-side-atomic writes
// were 100 MB of parasitic HBM traffic -- R13 lesson).
__global__ __launch_bounds__(512) void k_sort(const int* __restrict__ snd,
                                              const int* __restrict__ rcv,
                                              unsigned* __restrict__ rec_r,
                                              unsigned char* __restrict__ rec_s,
                                              unsigned short* __restrict__ srow_r,
                                              unsigned short* __restrict__ srow_s) {
    __shared__ int es[EPB], er[EPB];
    __shared__ unsigned scan[SB + 1];
    __shared__ unsigned cur[SB];
    __shared__ unsigned sorted[EPB];
    __shared__ unsigned char sorteds[EPB];
    int b = blockIdx.x, t = threadIdx.x;
    int base = b * EPB;
    int cnt = min(EPB, N_EDGES - base);
    for (int i = t; i < cnt; i += 512) { es[i] = snd[base + i]; er[i] = rcv[base + i]; }

    // ---- receiver stream ----
    for (int i = t; i < SB + 1; i += 512) scan[i] = 0u;
    __syncthreads();
    for (int i = t; i < cnt; i += 512) atomicAdd(&scan[(er[i] >> SBSH) + 1], 1u);
    __syncthreads();
    for (int off = 1; off < SB + 1; off <<= 1) {
        unsigned v = (t >= off && t < SB + 1) ? scan[t - off] : 0u;
        __syncthreads();
        if (t < SB + 1) scan[t] += v;
        __syncthreads();
    }
    for (int i = t; i < SB + 1; i += 512) srow_r[(size_t)b * (SB + 1) + i] = (unsigned short)scan[i];
    if (t < SB) cur[t] = scan[t];
    __syncthreads();
    for (int i = t; i < cnt; i += 512) {
        int r = er[i];
        unsigned pos = atomicAdd(&cur[r >> SBSH], 1u);
        sorted[pos] = ((unsigned)(r & 255) << 17) | (unsigned)es[i];
    }
    __syncthreads();
    for (int i = t; i < cnt; i += 512) rec_r[(size_t)base + i] = sorted[i];
    __syncthreads();

    // ---- sender stream (u8 local ids) ----
    for (int i = t; i < SB + 1; i += 512) scan[i] = 0u;
    __syncthreads();
    for (int i = t; i < cnt; i += 512) atomicAdd(&scan[(es[i] >> SBSH) + 1], 1u);
    __syncthreads();
    for (int off = 1; off < SB + 1; off <<= 1) {
        unsigned v = (t >= off && t < SB + 1) ? scan[t - off] : 0u;
        __syncthreads();
        if (t < SB + 1) scan[t] += v;
        __syncthreads();
    }
    for (int i = t; i < SB + 1; i += 512) srow_s[(size_t)b * (SB + 1) + i] = (unsigned short)scan[i];
    if (t < SB) cur[t] = scan[t];
    __syncthreads();
    for (int i = t; i < cnt; i += 512) {
        int s = es[i];
        unsigned pos = atomicAdd(&cur[s >> SBSH], 1u);
        sorteds[pos] = (unsigned char)(s & 255);
    }
    __syncthreads();
    for (int i = t; i < cnt; i += 512) rec_s[(size_t)base + i] = sorteds[i];
}

// sender-degree via per-bucket LDS histogram over sender-sorted runs
__global__ __launch_bounds__(512) void k_degs(const unsigned char* __restrict__ rec_s,
                                              const unsigned short* __restrict__ srow_s,
                                              float* __restrict__ rs_s) {
    __shared__ unsigned h[256];
    int s = blockIdx.x, t = threadIdx.x;
    if (t < 256) h[t] = 0u;
    __syncthreads();
    for (int k = t; k < NBLK; k += 512) {
        const unsigned short* row = srow_s + (size_t)k * (SB + 1);
        unsigned st = row[s], en = row[s + 1];
        const unsigned char* rp = rec_s + (size_t)k * EPB;
        for (unsigned i = st; i < en; ++i) atomicAdd(&h[rp[i]], 1u);
    }
    __syncthreads();
    if (t < 256) {
        int n = (s << SBSH) + t;
        if (n < N_NODES) rs_s[n] = rsqrtf(fmaxf((float)h[t], 1.0f));
    }
}

// per-bucket prefix over block segments: pref_t[s][k], totals gtot[s]
__global__ __launch_bounds__(256) void k_scanB(const unsigned short* __restrict__ srow_r,
                                               unsigned* __restrict__ pref_t,
                                               unsigned* __restrict__ gtot) {
    __shared__ unsigned buf[256];
    int s = blockIdx.x, t = threadIdx.x;
    unsigned run = 0;
    for (int k0 = 0; k0 < NBLK; k0 += 256) {
        int k = k0 + t;
        unsigned v = 0;
        if (k < NBLK) {
            const unsigned short* row = srow_r + (size_t)k * (SB + 1);
            v = (unsigned)row[s + 1] - (unsigned)row[s];
        }
        buf[t] = v;
        __syncthreads();
        for (int off = 1; off < 256; off <<= 1) {
            unsigned x = (t >= off) ? buf[t - off] : 0u;
            __syncthreads();
            buf[t] += x;
            __syncthreads();
        }
        if (k < NBLK) pref_t[(size_t)s * NBLK + k] = run + (buf[t] - v);
        unsigned tot = buf[255];
        __syncthreads();
        run += tot;
    }
    if (t == 0) gtot[s] = run;
}

// exclusive scan of bucket totals -> gbase[SB+1]
__global__ __launch_bounds__(512) void k_scanG(const unsigned* __restrict__ gtot,
                                               unsigned* __restrict__ gbase) {
    __shared__ unsigned buf[SB];
    int t = threadIdx.x;
    if (t < SB) buf[t] = gtot[t];
    __syncthreads();
    for (int off = 1; off < SB; off <<= 1) {
        unsigned x = (t >= off && t < SB) ? buf[t - off] : 0u;
        __syncthreads();
        if (t < SB) buf[t] += x;
        __syncthreads();
    }
    if (t < SB) gbase[t + 1] = buf[t];
    if (t == 0) gbase[0] = 0u;
}

// scatter block-sorted records to global bucket-sorted order
__global__ __launch_bounds__(256) void k_gscat(const unsigned* __restrict__ rec_r,
                                               const unsigned short* __restrict__ srow_r,
                                               const unsigned* __restrict__ pref_t,
                                               const unsigned* __restrict__ gbase,
                                               unsigned* __restrict__ grec) {
    __shared__ unsigned recs[EPB];
    __shared__ unsigned short srow[SB + 1];
    int b = blockIdx.x, t = threadIdx.x;
    int base = b * EPB;
    int cnt = min(EPB, N_EDGES - base);
    for (int i = t; i < cnt; i += 256) recs[i] = rec_r[(size_t)base + i];
    for (int i = t; i < SB + 1; i += 256) srow[i] = srow_r[(size_t)b * (SB + 1) + i];
    __syncthreads();
    for (int s = t; s < SB; s += 256) {
        unsigned lo = srow[s], hi = srow[s + 1];
        if (lo == hi) continue;
        unsigned dst = gbase[s] + pref_t[(size_t)s * NBLK + b];
        for (unsigned i = lo; i < hi; ++i) grec[dst + (i - lo)] = recs[i];
    }
}

// within-bucket counting sort by local receiver (in-place) + CSR row_ptr
__global__ __launch_bounds__(256) void k_sort2(unsigned* __restrict__ grec,
                                               const unsigned* __restrict__ gbase,
                                               unsigned* __restrict__ row_ptr) {
    __shared__ unsigned recs[S2CAP];     // 48 KB
    __shared__ unsigned hist[256];
    __shared__ unsigned scan[256];
    __shared__ unsigned cur[256];
    int s = blockIdx.x, t = threadIdx.x;
    unsigned lo = gbase[s], hi = gbase[s + 1];
    unsigned cnt = min(hi - lo, (unsigned)S2CAP);
    for (unsigned i = t; i < cnt; i += 256) recs[i] = grec[lo + i];
    hist[t] = 0u;
    __syncthreads();
    for (unsigned i = t; i < cnt; i += 256) atomicAdd(&hist[recs[i] >> 17], 1u);
    __syncthreads();
    unsigned v = hist[t];
    scan[t] = v;
    __syncthreads();
    for (int off = 1; off < 256; off <<= 1) {
        unsigned x = (t >= off) ? scan[t - off] : 0u;
        __syncthreads();
        scan[t] += x;
        __syncthreads();
    }
    unsigned excl = scan[t] - v;   // exclusive prefix of bin t
    {
        int n = (s << SBSH) + t;
        if (n <= N_NODES) row_ptr[n] = lo + excl;
    }
    cur[t] = excl;
    __syncthreads();
    for (unsigned i = t; i < cnt; i += 256) {
        unsigned rec = recs[i];
        unsigned pos = atomicAdd(&cur[rec >> 17], 1u);
        grec[lo + pos] = rec & 0x1FFFFu;   // sender only
    }
}

// pure CSR gather: 5 lanes per node, one float4 each; zero atomics.
__global__ __launch_bounds__(320) void k_gather(const unsigned* __restrict__ row_ptr,
                                                const unsigned* __restrict__ grec,
                                                const float* __restrict__ src,
                                                float* __restrict__ dst) {
    int gid = blockIdx.x * 320 + threadIdx.x;
    int node = gid / 5, q = gid % 5;
    if (node >= N_NODES) return;
    unsigned lo = row_ptr[node], hi = row_ptr[node + 1];
    float4 acc = make_float4(0.f, 0.f, 0.f, 0.f);
    float4 acc2 = make_float4(0.f, 0.f, 0.f, 0.f);
    unsigned e = lo;
    for (; e + 2 <= hi; e += 2) {
        unsigned sa = grec[e], sb = grec[e + 1];
        float4 v1 = ((const float4*)src)[sa * 5 + q];
        float4 v2 = ((const float4*)src)[sb * 5 + q];
        acc.x += v1.x; acc.y += v1.y; acc.z += v1.z; acc.w += v1.w;
        acc2.x += v2.x; acc2.y += v2.y; acc2.z += v2.z; acc2.w += v2.w;
    }
    if (e < hi) {
        unsigned sa = grec[e];
        float4 v1 = ((const float4*)src)[sa * 5 + q];
        acc.x += v1.x; acc.y += v1.y; acc.z += v1.z; acc.w += v1.w;
    }
    acc.x += acc2.x; acc.y += acc2.y; acc.z += acc2.z; acc.w += acc2.w;
    float sc = rsqrtf(fmaxf((float)(hi - lo), 1.0f));
    acc.x *= sc; acc.y *= sc; acc.z *= sc; acc.w *= sc;
    ((float4*)dst)[node * 5 + q] = acc;
}

// GC layer 1: thread-per-node, nodes staged through LDS in coalesced
// 16-float K-chunks (pad-17 rows -> conflict-free b32 reads), weights s_load.
__global__ __launch_bounds__(128) void k_gc1(const float* __restrict__ nodes,
                                             const float* __restrict__ W1,
                                             const float* __restrict__ b1,
                                             const float* __restrict__ rs_s,
                                             float* __restrict__ h_pre) {
    __shared__ float tile[GCB * 17];
    int t = threadIdx.x;
    int n0 = blockIdx.x * GCB;
    int node = n0 + t;
    float acc[GC_HID];
#pragma unroll
    for (int j = 0; j < GC_HID; ++j) acc[j] = b1[j];

    int r = t >> 2, c4 = t & 3;
    for (int ch = 0; ch < 16; ++ch) {
        __syncthreads();
#pragma unroll
        for (int i = 0; i < 4; ++i) {
            int row = r + i * 32;
            int gn = n0 + row;
            float4 v = (gn < N_NODES)
                ? ((const float4*)nodes)[(size_t)gn * 64 + ch * 4 + c4]
                : make_float4(0.f, 0.f, 0.f, 0.f);
            float* dst = &tile[row * 17 + c4 * 4];
            dst[0] = v.x; dst[1] = v.y; dst[2] = v.z; dst[3] = v.w;
        }
        __syncthreads();
        const float* wb = W1 + ch * 16 * GC_HID;
#pragma unroll
        for (int kk = 0; kk < 16; ++kk) {
            float x = tile[t * 17 + kk];
            const float* wr = wb + kk * GC_HID;
#pragma unroll
            for (int j = 0; j < GC_HID; ++j) acc[j] = fmaf(x, wr[j], acc[j]);
        }
    }
    if (node >= N_NODES) return;
    float mx = -1e30f;
#pragma unroll
    for (int j = 0; j < GC_HID; ++j) {
        acc[j] = fmaxf(acc[j], 0.0f);
        mx = fmaxf(mx, acc[j]);
    }
    float s = 0.0f;
#pragma unroll
    for (int j = 0; j < GC_HID; ++j) {
        acc[j] = __expf(acc[j] - mx);
        s += acc[j];
    }
    float inv = rs_s[node] / s;
#pragma unroll
    for (int j = 0; j < GC_HID; ++j) acc[j] *= inv;
    float4* o = (float4*)&h_pre[(size_t)node * GC_HID];
    o[0] = make_float4(acc[0],  acc[1],  acc[2],  acc[3]);
    o[1] = make_float4(acc[4],  acc[5],  acc[6],  acc[7]);
    o[2] = make_float4(acc[8],  acc[9],  acc[10], acc[11]);
    o[3] = make_float4(acc[12], acc[13], acc[14], acc[15]);
    o[4] = make_float4(acc[16], acc[17], acc[18], acc[19]);
}

// GC layer 2 transform: h2_pre = softmax(relu(h1@W2+b2)) * rs_s
__global__ __launch_bounds__(256) void k_gc2(const float* __restrict__ h1in,
                                             const float* __restrict__ W2,
                                             const float* __restrict__ b2,
                                             const float* __restrict__ rs_s,
                                             float* __restrict__ h2_pre) {
    __shared__ float Wsh[GC_HID * GC_HID];
    __shared__ float bsh[GC_HID];
    int tid = threadIdx.x;
    if (tid < GC_HID * GC_HID) Wsh[tid] = W2[tid];
    if (tid < GC_HID) bsh[tid] = b2[tid];
    __syncthreads();
    int node = blockIdx.x * 256 + tid;
    if (node >= N_NODES) return;
    const float4* ap = (const float4*)&h1in[node * GC_HID];
    float4 a0 = ap[0], a1 = ap[1], a2 = ap[2], a3 = ap[3], a4 = ap[4];
    float h1[GC_HID] = {a0.x,a0.y,a0.z,a0.w, a1.x,a1.y,a1.z,a1.w,
                        a2.x,a2.y,a2.z,a2.w, a3.x,a3.y,a3.z,a3.w,
                        a4.x,a4.y,a4.z,a4.w};
    float t[GC_HID];
#pragma unroll
    for (int j = 0; j < GC_HID; ++j) t[j] = bsh[j];
#pragma unroll
    for (int i = 0; i < GC_HID; ++i) {
        float x = h1[i];
#pragma unroll
        for (int j = 0; j < GC_HID; ++j) t[j] = fmaf(x, Wsh[i * GC_HID + j], t[j]);
    }
    float mx = -1e30f;
#pragma unroll
    for (int j = 0; j < GC_HID; ++j) { t[j] = fmaxf(t[j], 0.0f); mx = fmaxf(mx, t[j]); }
    float s = 0.0f;
#pragma unroll
    for (int j = 0; j < GC_HID; ++j) { t[j] = __expf(t[j] - mx); s += t[j]; }
    float inv = rs_s[node] / s;
#pragma unroll
    for (int j = 0; j < GC_HID; ++j) t[j] *= inv;
    float4* o = (float4*)&h2_pre[node * GC_HID];
    o[0] = make_float4(t[0],  t[1],  t[2],  t[3]);
    o[1] = make_float4(t[4],  t[5],  t[6],  t[7]);
    o[2] = make_float4(t[8],  t[9],  t[10], t[11]);
    o[3] = make_float4(t[12], t[13], t[14], t[15]);
    o[4] = make_float4(t[16], t[17], t[18], t[19]);
}

// fused encoder head, 8 waves/block: wave = (half<<2)|node_group.
// half forced wave-uniform via readfirstlane -> weights stay s_load.
__global__ __launch_bounds__(512) void k_encf(const float* __restrict__ h2in,
                                              const float* __restrict__ nodes,
                                              const float* __restrict__ Wmu,
                                              const float* __restrict__ bmu,
                                              const float* __restrict__ Wls,
                                              const float* __restrict__ bls,
                                              float* __restrict__ mu_out,
                                              float* __restrict__ ls_out) {
    __shared__ float tile[ENB * 17];   // 17,408 B
    int t = threadIdx.x;
    int wave = t >> 6, lane = t & 63;
    int ng = wave & 3;                 // node group within block
    int half = __builtin_amdgcn_readfirstlane(wave >> 2);  // 0 = mu, 1 = ls
    int n0 = blockIdx.x * ENB;
    int lrow = ng * 64 + lane;
    int node = n0 + lrow;
    const float* W  = half ? Wls : Wmu;
    const float* bb = half ? bls : bmu;
    float* out      = half ? ls_out : mu_out;

    float acc[Z_DIM];
#pragma unroll
    for (int j = 0; j < Z_DIM; ++j) acc[j] = bb[j];

    if (node < N_NODES) {
        const float4* hp = (const float4*)(h2in + (size_t)node * GC_HID);
#pragma unroll
        for (int v = 0; v < 5; ++v) {
            float4 hh = hp[v];
#pragma unroll
            for (int c = 0; c < 4; ++c) {
                float x = (c == 0) ? hh.x : (c == 1) ? hh.y : (c == 2) ? hh.z : hh.w;
                const float* wr = W + (v * 4 + c) * Z_DIM;
#pragma unroll
                for (int j = 0; j < Z_DIM; ++j) acc[j] = fmaf(x, wr[j], acc[j]);
            }
        }
    }
    for (int ch = 0; ch < 16; ++ch) {
        __syncthreads();
#pragma unroll
        for (int rep = 0; rep < 2; ++rep) {
            int idx = rep * 512 + t;       // 0..1023
            int row = idx >> 2, k4 = idx & 3;
            int gn = n0 + row;
            float4 v = (gn < N_NODES)
                ? ((const float4*)nodes)[(size_t)gn * 64 + ch * 4 + k4]
                : make_float4(0.f, 0.f, 0.f, 0.f);
            float* dst = &tile[row * 17 + k4 * 4];
            dst[0] = v.x; dst[1] = v.y; dst[2] = v.z; dst[3] = v.w;
        }
        __syncthreads();
#pragma unroll
        for (int kk = 0; kk < 16; ++kk) {
            float x = tile[lrow * 17 + kk];
            const float* wr = W + (GC_HID + ch * 16 + kk) * Z_DIM;
#pragma unroll
            for (int j = 0; j < Z_DIM; ++j) acc[j] = fmaf(x, wr[j], acc[j]);
        }
    }
    if (node >= N_NODES) return;
    float4* op = (float4*)(out + (size_t)node * Z_DIM);
#pragma unroll
    for (int v = 0; v < Z_DIM / 4; ++v)
        op[v] = make_float4(acc[4*v], acc[4*v+1], acc[4*v+2], acc[4*v+3]);
}

// reparameterization: z = mu + (1e-4 + exp(0.5*ls)) * eps
__global__ __launch_bounds__(256) void k_z(const float* __restrict__ mu,
                                           const float* __restrict__ ls,
                                           const float* __restrict__ eps,
                                           float* __restrict__ z) {
    int i = blockIdx.x * 256 + threadIdx.x;
    if (i >= N_NODES * Z_DIM / 4) return;
    float4 m = ((const float4*)mu)[i];
    float4 l = ((const float4*)ls)[i];
    float4 e = ((const float4*)eps)[i];
    float4 zz;
    zz.x = m.x + (1e-4f + __expf(0.5f * l.x)) * e.x;
    zz.y = m.y + (1e-4f + __expf(0.5f * l.y)) * e.y;
    zz.z = m.z + (1e-4f + __expf(0.5f * l.z)) * e.z;
    zz.w = m.w + (1e-4f + __expf(0.5f * l.w)) * e.w;
    ((float4*)z)[i] = zz;
}

// decoder stage 1: d = relu(z@Wd1+bd1), thread per node (weights uniform)
__global__ __launch_bounds__(256) void k_decd(const float* __restrict__ z,
                                              const float* __restrict__ Wd1,
                                              const float* __restrict__ bd1,
                                              float* __restrict__ dbuf) {
    int node = blockIdx.x * 256 + threadIdx.x;
    if (node >= N_NODES) return;
    float d[DEC_HID];
#pragma unroll
    for (int j = 0; j < DEC_HID; ++j) d[j] = bd1[j];
    const float4* zp = (const float4*)(z + (size_t)node * Z_DIM);
#pragma unroll
    for (int v = 0; v < Z_DIM / 4; ++v) {
        float4 zz = zp[v];
#pragma unroll
        for (int c = 0; c < 4; ++c) {
            float x = (c == 0) ? zz.x : (c == 1) ? zz.y : (c == 2) ? zz.z : zz.w;
            const float* wr = Wd1 + (v * 4 + c) * DEC_HID;
#pragma unroll
            for (int j = 0; j < DEC_HID; ++j) d[j] = fmaf(x, wr[j], d[j]);
        }
    }
    float4* op = (float4*)(dbuf + (size_t)node * DEC_HID);
#pragma unroll
    for (int v = 0; v < DEC_HID / 4; ++v)
        op[v] = make_float4(fmaxf(d[4*v], 0.f), fmaxf(d[4*v+1], 0.f),
                            fmaxf(d[4*v+2], 0.f), fmaxf(d[4*v+3], 0.f));
}

// decoder stage 2: chunk id forced wave-uniform via readfirstlane; lane = node.
__global__ __launch_bounds__(256) void k_decx(const float* __restrict__ dbuf,
                                              const float* __restrict__ Wd2,
                                              const float* __restrict__ bd2,
                                              float* __restrict__ X) {
    int lane = threadIdx.x & 63;
    int wv   = threadIdx.x >> 6;             // 0..3
    int ch   = __builtin_amdgcn_readfirstlane(((blockIdx.x & 1) << 2) | wv);
    int node = (blockIdx.x >> 1) * 64 + lane;
    if (node >= N_NODES) return;
    int co = ch << 5;
    float o[32];
#pragma unroll
    for (int j = 0; j < 32; ++j) o[j] = bd2[co + j];
    const float4* dp = (const float4*)(dbuf + (size_t)node * DEC_HID);
#pragma unroll
    for (int v = 0; v < DEC_HID / 4; ++v) {
        float4 dd = dp[v];
#pragma unroll
        for (int c = 0; c < 4; ++c) {
            float x = (c == 0) ? dd.x : (c == 1) ? dd.y : (c == 2) ? dd.z : dd.w;
            const float* wr = Wd2 + (v * 4 + c) * D_FEAT + co;
#pragma unroll
            for (int j = 0; j < 32; ++j) o[j] = fmaf(x, wr[j], o[j]);
        }
    }
    float4* xp = (float4*)(X + (size_t)node * D_FEAT + co);
#pragma unroll
    for (int v = 0; v < 8; ++v)
        xp[v] = make_float4(o[4*v], o[4*v+1], o[4*v+2], o[4*v+3]);
}

extern "C" void kernel_launch(void* const* d_in, const int* in_sizes, int n_in,
                              void* d_out, int out_size, void* d_ws, size_t ws_size,
                              hipStream_t stream) {
    const float* nodes = (const float*)d_in[0];
    const int*   snd   = (const int*)d_in[1];
    const int*   rcv   = (const int*)d_in[2];
    const float* eps   = (const float*)d_in[3];
    const float* W1    = (const float*)d_in[4];
    const float* b1    = (const float*)d_in[5];
    const float* W2    = (const float*)d_in[6];
    const float* b2    = (const float*)d_in[7];
    const float* Wmu   = (const float*)d_in[8];
    const float* bmu   = (const float*)d_in[9];
    const float* Wls   = (const float*)d_in[10];
    const float* bls   = (const float*)d_in[11];
    const float* Wd1   = (const float*)d_in[12];
    const float* bd1   = (const float*)d_in[13];
    const float* Wd2   = (const float*)d_in[14];
    const float* bd2   = (const float*)d_in[15];

    char* ws = (char*)d_ws;
    float*          h_pre    = (float*)(ws);
    float*          agg      = (float*)(ws + 8000000);
    float*          dbuf     = (float*)(ws);              // overlays h_pre+agg (dead)
    unsigned*       grec     = (unsigned*)(ws + 16000000);
    unsigned*       rec_r    = (unsigned*)(ws + 28804096);
    unsigned short* srow_r   = (unsigned short*)(ws + 41608192);
    unsigned*       pref_t   = (unsigned*)(ws + 42836720);
    float*          zbuf     = (float*)(ws + 28804096);   // reuses rec_r zone after gscat
    unsigned*       row_ptr  = (unsigned*)(ws + 45287504);
    unsigned*       gtot     = (unsigned*)(ws + 45687508);
    unsigned*       gbase    = (unsigned*)(ws + 45689076);
    float*          rs_s     = (float*)(ws + 45690648);
    unsigned char*  rec_s    = (unsigned char*)(ws + 46090648);
    unsigned short* srow_s   = (unsigned short*)(ws + 49291672);

    float* X      = (float*)d_out;
    float* mu_out = X + (size_t)N_NODES * D_FEAT;
    float* ls_out = mu_out + (size_t)N_NODES * Z_DIM;

    k_sort<<<NBLK, 512, 0, stream>>>(snd, rcv, rec_r, rec_s, srow_r, srow_s);
    k_degs<<<SB, 512, 0, stream>>>(rec_s, srow_s, rs_s);
    k_scanB<<<SB, 256, 0, stream>>>(srow_r, pref_t, gtot);
    k_scanG<<<1, 512, 0, stream>>>(gtot, gbase);
    k_gscat<<<NBLK, 256, 0, stream>>>(rec_r, srow_r, pref_t, gbase, grec);
    k_sort2<<<SB, 256, 0, stream>>>(grec, gbase, row_ptr);

    k_gc1<<<782, 128, 0, stream>>>(nodes, W1, b1, rs_s, h_pre);
    k_gather<<<1563, 320, 0, stream>>>(row_ptr, grec, h_pre, agg);
    k_gc2<<<391, 256, 0, stream>>>(agg, W2, b2, rs_s, h_pre);
    k_gather<<<1563, 320, 0, stream>>>(row_ptr, grec, h_pre, agg);

    k_encf<<<391, 512, 0, stream>>>(agg, nodes, Wmu, bmu, Wls, bls,
                                    mu_out, ls_out);
    k_z<<<3125, 256, 0, stream>>>(mu_out, ls_out, eps, zbuf);
    k_decd<<<391, 256, 0, stream>>>(zbuf, Wd1, bd1, dbuf);
    k_decx<<<3126, 256, 0, stream>>>(dbuf, Wd2, bd2, X);
}

// Round 15
// 480.733 us; speedup vs baseline: 1.2398x; 1.0396x over previous
//
#include <hip/hip_runtime.h>
#include <math.h>

#define N_NODES 100000
#define N_EDGES 3200000
#define D_FEAT 256
#define GC_HID 20
#define DEC_HID 40
#define Z_DIM 32

#define EPB 2048          // edges per sort block
#define NBLK 1563         // ceil(3.2M / 2048)
#define SB 392            // node buckets of 256 (392*256 = 100352)
#define SBSH 8
#define S2CAP 12288       // per-bucket record cap
#define GCB 128           // nodes per block for k_gc1 (782 blocks)
#define ENB 128           // nodes per block for k_encf (782 blocks, 4 waves)

// ---------------- ws layout (bytes) ----------------
// h_pre  @ 0           8,000,000   (dead after 2nd gather; dbuf overlays @0)
// agg    @ 8,000,000   8,000,000   (dead after k_encf)
// dbuf   @ 0          16,000,000   (k_decd output; overlays h_pre+agg)
// grec   @16,000,000  12,804,096   (bucket-sorted records; dead after 2nd gather)
// zone Z @28,804,096:
//   rec_r  @28,804,096 12,804,096  (dead after k_gscat)
//   srow_r @41,608,192  1,228,518  (dead after k_gscat)
//   pref_t @42,836,720  2,450,784  (dead after k_gscat)
//   zbuf   @28,804,096 12,800,000  (k_z output, after gscat)
// row_ptr @45,287,504    400,004
// gtot    @45,687,508      1,568
// gbase   @45,689,076      1,572
// rs_s    @45,690,648    400,000
// rec_s   @46,090,648  3,201,024   (u8 sender-sorted stream)
// srow_s  @49,291,672  1,228,518   end = 50,520,190

// dual block-local counting sort (receiver u32 + sender u8 streams).
// ZERO global atomics (R13 lesson: each device-scope atomic costs a
// memory-side write transaction; 3.2M of them = 100 MB parasitic HBM).
__global__ __launch_bounds__(512) void k_sort(const int* __restrict__ snd,
                                              const int* __restrict__ rcv,
                                              unsigned* __restrict__ rec_r,
                                              unsigned char* __restrict__ rec_s,
                                              unsigned short* __restrict__ srow_r,
                                              unsigned short* __restrict__ srow_s) {
    __shared__ int es[EPB], er[EPB];
    __shared__ unsigned scan[SB + 1];
    __shared__ unsigned cur[SB];
    __shared__ unsigned sorted[EPB];
    __shared__ unsigned char sorteds[EPB];
    int b = blockIdx.x, t = threadIdx.x;
    int base = b * EPB;
    int cnt = min(EPB, N_EDGES - base);
    for (int i = t; i < cnt; i += 512) { es[i] = snd[base + i]; er[i] = rcv[base + i]; }

    // ---- receiver stream ----
    for (int i = t; i < SB + 1; i += 512) scan[i] = 0u;
    __syncthreads();
    for (int i = t; i < cnt; i += 512) atomicAdd(&scan[(er[i] >> SBSH) + 1], 1u);
    __syncthreads();
    for (int off = 1; off < SB + 1; off <<= 1) {
        unsigned v = (t >= off && t < SB + 1) ? scan[t - off] : 0u;
        __syncthreads();
        if (t < SB + 1) scan[t] += v;
        __syncthreads();
    }
    for (int i = t; i < SB + 1; i += 512) srow_r[(size_t)b * (SB + 1) + i] = (unsigned short)scan[i];
    if (t < SB) cur[t] = scan[t];
    __syncthreads();
    for (int i = t; i < cnt; i += 512) {
        int r = er[i];
        unsigned pos = atomicAdd(&cur[r >> SBSH], 1u);
        sorted[pos] = ((unsigned)(r & 255) << 17) | (unsigned)es[i];
    }
    __syncthreads();
    for (int i = t; i < cnt; i += 512) rec_r[(size_t)base + i] = sorted[i];
    __syncthreads();

    // ---- sender stream (u8 local ids) ----
    for (int i = t; i < SB + 1; i += 512) scan[i] = 0u;
    __syncthreads();
    for (int i = t; i < cnt; i += 512) atomicAdd(&scan[(es[i] >> SBSH) + 1], 1u);
    __syncthreads();
    for (int off = 1; off < SB + 1; off <<= 1) {
        unsigned v = (t >= off && t < SB + 1) ? scan[t - off] : 0u;
        __syncthreads();
        if (t < SB + 1) scan[t] += v;
        __syncthreads();
    }
    for (int i = t; i < SB + 1; i += 512) srow_s[(size_t)b * (SB + 1) + i] = (unsigned short)scan[i];
    if (t < SB) cur[t] = scan[t];
    __syncthreads();
    for (int i = t; i < cnt; i += 512) {
        int s = es[i];
        unsigned pos = atomicAdd(&cur[s >> SBSH], 1u);
        sorteds[pos] = (unsigned char)(s & 255);
    }
    __syncthreads();
    for (int i = t; i < cnt; i += 512) rec_s[(size_t)base + i] = sorteds[i];
}

// sender-degree via per-bucket LDS histogram over sender-sorted runs
__global__ __launch_bounds__(512) void k_degs(const unsigned char* __restrict__ rec_s,
                                              const unsigned short* __restrict__ srow_s,
                                              float* __restrict__ rs_s) {
    __shared__ unsigned h[256];
    int s = blockIdx.x, t = threadIdx.x;
    if (t < 256) h[t] = 0u;
    __syncthreads();
    for (int k = t; k < NBLK; k += 512) {
        const unsigned short* row = srow_s + (size_t)k * (SB + 1);
        unsigned st = row[s], en = row[s + 1];
        const unsigned char* rp = rec_s + (size_t)k * EPB;
        for (unsigned i = st; i < en; ++i) atomicAdd(&h[rp[i]], 1u);
    }
    __syncthreads();
    if (t < 256) {
        int n = (s << SBSH) + t;
        if (n < N_NODES) rs_s[n] = rsqrtf(fmaxf((float)h[t], 1.0f));
    }
}

// per-bucket prefix over block segments: pref_t[s][k], totals gtot[s]
__global__ __launch_bounds__(256) void k_scanB(const unsigned short* __restrict__ srow_r,
                                               unsigned* __restrict__ pref_t,
                                               unsigned* __restrict__ gtot) {
    __shared__ unsigned buf[256];
    int s = blockIdx.x, t = threadIdx.x;
    unsigned run = 0;
    for (int k0 = 0; k0 < NBLK; k0 += 256) {
        int k = k0 + t;
        unsigned v = 0;
        if (k < NBLK) {
            const unsigned short* row = srow_r + (size_t)k * (SB + 1);
            v = (unsigned)row[s + 1] - (unsigned)row[s];
        }
        buf[t] = v;
        __syncthreads();
        for (int off = 1; off < 256; off <<= 1) {
            unsigned x = (t >= off) ? buf[t - off] : 0u;
            __syncthreads();
            buf[t] += x;
            __syncthreads();
        }
        if (k < NBLK) pref_t[(size_t)s * NBLK + k] = run + (buf[t] - v);
        unsigned tot = buf[255];
        __syncthreads();
        run += tot;
    }
    if (t == 0) gtot[s] = run;
}

// exclusive scan of bucket totals -> gbase[SB+1]
__global__ __launch_bounds__(512) void k_scanG(const unsigned* __restrict__ gtot,
                                               unsigned* __restrict__ gbase) {
    __shared__ unsigned buf[SB];
    int t = threadIdx.x;
    if (t < SB) buf[t] = gtot[t];
    __syncthreads();
    for (int off = 1; off < SB; off <<= 1) {
        unsigned x = (t >= off && t < SB) ? buf[t - off] : 0u;
        __syncthreads();
        if (t < SB) buf[t] += x;
        __syncthreads();
    }
    if (t < SB) gbase[t + 1] = buf[t];
    if (t == 0) gbase[0] = 0u;
}

// scatter block-sorted records to global bucket-sorted order
__global__ __launch_bounds__(256) void k_gscat(const unsigned* __restrict__ rec_r,
                                               const unsigned short* __restrict__ srow_r,
                                               const unsigned* __restrict__ pref_t,
                                               const unsigned* __restrict__ gbase,
                                               unsigned* __restrict__ grec) {
    __shared__ unsigned recs[EPB];
    __shared__ unsigned short srow[SB + 1];
    int b = blockIdx.x, t = threadIdx.x;
    int base = b * EPB;
    int cnt = min(EPB, N_EDGES - base);
    for (int i = t; i < cnt; i += 256) recs[i] = rec_r[(size_t)base + i];
    for (int i = t; i < SB + 1; i += 256) srow[i] = srow_r[(size_t)b * (SB + 1) + i];
    __syncthreads();
    for (int s = t; s < SB; s += 256) {
        unsigned lo = srow[s], hi = srow[s + 1];
        if (lo == hi) continue;
        unsigned dst = gbase[s] + pref_t[(size_t)s * NBLK + b];
        for (unsigned i = lo; i < hi; ++i) grec[dst + (i - lo)] = recs[i];
    }
}

// within-bucket counting sort by local receiver (in-place) + CSR row_ptr
__global__ __launch_bounds__(256) void k_sort2(unsigned* __restrict__ grec,
                                               const unsigned* __restrict__ gbase,
                                               unsigned* __restrict__ row_ptr) {
    __shared__ unsigned recs[S2CAP];     // 48 KB
    __shared__ unsigned hist[256];
    __shared__ unsigned scan[256];
    __shared__ unsigned cur[256];
    int s = blockIdx.x, t = threadIdx.x;
    unsigned lo = gbase[s], hi = gbase[s + 1];
    unsigned cnt = min(hi - lo, (unsigned)S2CAP);
    for (unsigned i = t; i < cnt; i += 256) recs[i] = grec[lo + i];
    hist[t] = 0u;
    __syncthreads();
    for (unsigned i = t; i < cnt; i += 256) atomicAdd(&hist[recs[i] >> 17], 1u);
    __syncthreads();
    unsigned v = hist[t];
    scan[t] = v;
    __syncthreads();
    for (int off = 1; off < 256; off <<= 1) {
        unsigned x = (t >= off) ? scan[t - off] : 0u;
        __syncthreads();
        scan[t] += x;
        __syncthreads();
    }
    unsigned excl = scan[t] - v;   // exclusive prefix of bin t
    {
        int n = (s << SBSH) + t;
        if (n <= N_NODES) row_ptr[n] = lo + excl;
    }
    cur[t] = excl;
    __syncthreads();
    for (unsigned i = t; i < cnt; i += 256) {
        unsigned rec = recs[i];
        unsigned pos = atomicAdd(&cur[rec >> 17], 1u);
        grec[lo + pos] = rec & 0x1FFFFu;   // sender only
    }
}

// pure CSR gather: 5 lanes per node, one float4 each; zero atomics.
// 4-way unrolled edge loop: 4 independent load chains to hide L2/L3 latency.
__global__ __launch_bounds__(320) void k_gather(const unsigned* __restrict__ row_ptr,
                                                const unsigned* __restrict__ grec,
                                                const float* __restrict__ src,
                                                float* __restrict__ dst) {
    int gid = blockIdx.x * 320 + threadIdx.x;
    int node = gid / 5, q = gid % 5;
    if (node >= N_NODES) return;
    unsigned lo = row_ptr[node], hi = row_ptr[node + 1];
    float4 a0 = make_float4(0.f, 0.f, 0.f, 0.f);
    float4 a1 = make_float4(0.f, 0.f, 0.f, 0.f);
    float4 a2 = make_float4(0.f, 0.f, 0.f, 0.f);
    float4 a3 = make_float4(0.f, 0.f, 0.f, 0.f);
    unsigned e = lo;
    for (; e + 4 <= hi; e += 4) {
        unsigned s0 = grec[e], s1 = grec[e + 1], s2 = grec[e + 2], s3 = grec[e + 3];
        float4 v0 = ((const float4*)src)[s0 * 5 + q];
        float4 v1 = ((const float4*)src)[s1 * 5 + q];
        float4 v2 = ((const float4*)src)[s2 * 5 + q];
        float4 v3 = ((const float4*)src)[s3 * 5 + q];
        a0.x += v0.x; a0.y += v0.y; a0.z += v0.z; a0.w += v0.w;
        a1.x += v1.x; a1.y += v1.y; a1.z += v1.z; a1.w += v1.w;
        a2.x += v2.x; a2.y += v2.y; a2.z += v2.z; a2.w += v2.w;
        a3.x += v3.x; a3.y += v3.y; a3.z += v3.z; a3.w += v3.w;
    }
    for (; e < hi; ++e) {
        unsigned s0 = grec[e];
        float4 v0 = ((const float4*)src)[s0 * 5 + q];
        a0.x += v0.x; a0.y += v0.y; a0.z += v0.z; a0.w += v0.w;
    }
    a0.x += a1.x + a2.x + a3.x;
    a0.y += a1.y + a2.y + a3.y;
    a0.z += a1.z + a2.z + a3.z;
    a0.w += a1.w + a2.w + a3.w;
    float sc = rsqrtf(fmaxf((float)(hi - lo), 1.0f));
    a0.x *= sc; a0.y *= sc; a0.z *= sc; a0.w *= sc;
    ((float4*)dst)[node * 5 + q] = a0;
}

// GC layer 1: thread-per-node, nodes staged through LDS in coalesced
// 16-float K-chunks (pad-17 rows -> conflict-free b32 reads), weights s_load.
__global__ __launch_bounds__(128) void k_gc1(const float* __restrict__ nodes,
                                             const float* __restrict__ W1,
                                             const float* __restrict__ b1,
                                             const float* __restrict__ rs_s,
                                             float* __restrict__ h_pre) {
    __shared__ float tile[GCB * 17];
    int t = threadIdx.x;
    int n0 = blockIdx.x * GCB;
    int node = n0 + t;
    float acc[GC_HID];
#pragma unroll
    for (int j = 0; j < GC_HID; ++j) acc[j] = b1[j];

    int r = t >> 2, c4 = t & 3;
    for (int ch = 0; ch < 16; ++ch) {
        __syncthreads();
#pragma unroll
        for (int i = 0; i < 4; ++i) {
            int row = r + i * 32;
            int gn = n0 + row;
            float4 v = (gn < N_NODES)
                ? ((const float4*)nodes)[(size_t)gn * 64 + ch * 4 + c4]
                : make_float4(0.f, 0.f, 0.f, 0.f);
            float* dst = &tile[row * 17 + c4 * 4];
            dst[0] = v.x; dst[1] = v.y; dst[2] = v.z; dst[3] = v.w;
        }
        __syncthreads();
        const float* wb = W1 + ch * 16 * GC_HID;
#pragma unroll
        for (int kk = 0; kk < 16; ++kk) {
            float x = tile[t * 17 + kk];
            const float* wr = wb + kk * GC_HID;
#pragma unroll
            for (int j = 0; j < GC_HID; ++j) acc[j] = fmaf(x, wr[j], acc[j]);
        }
    }
    if (node >= N_NODES) return;
    float mx = -1e30f;
#pragma unroll
    for (int j = 0; j < GC_HID; ++j) {
        acc[j] = fmaxf(acc[j], 0.0f);
        mx = fmaxf(mx, acc[j]);
    }
    float s = 0.0f;
#pragma unroll
    for (int j = 0; j < GC_HID; ++j) {
        acc[j] = __expf(acc[j] - mx);
        s += acc[j];
    }
    float inv = rs_s[node] / s;
#pragma unroll
    for (int j = 0; j < GC_HID; ++j) acc[j] *= inv;
    float4* o = (float4*)&h_pre[(size_t)node * GC_HID];
    o[0] = make_float4(acc[0],  acc[1],  acc[2],  acc[3]);
    o[1] = make_float4(acc[4],  acc[5],  acc[6],  acc[7]);
    o[2] = make_float4(acc[8],  acc[9],  acc[10], acc[11]);
    o[3] = make_float4(acc[12], acc[13], acc[14], acc[15]);
    o[4] = make_float4(acc[16], acc[17], acc[18], acc[19]);
}

// GC layer 2 transform: h2_pre = softmax(relu(h1@W2+b2)) * rs_s
__global__ __launch_bounds__(256) void k_gc2(const float* __restrict__ h1in,
                                             const float* __restrict__ W2,
                                             const float* __restrict__ b2,
                                             const float* __restrict__ rs_s,
                                             float* __restrict__ h2_pre) {
    __shared__ float Wsh[GC_HID * GC_HID];
    __shared__ float bsh[GC_HID];
    int tid = threadIdx.x;
    if (tid < GC_HID * GC_HID) Wsh[tid] = W2[tid];
    if (tid < GC_HID) bsh[tid] = b2[tid];
    __syncthreads();
    int node = blockIdx.x * 256 + tid;
    if (node >= N_NODES) return;
    const float4* ap = (const float4*)&h1in[node * GC_HID];
    float4 a0 = ap[0], a1 = ap[1], a2 = ap[2], a3 = ap[3], a4 = ap[4];
    float h1[GC_HID] = {a0.x,a0.y,a0.z,a0.w, a1.x,a1.y,a1.z,a1.w,
                        a2.x,a2.y,a2.z,a2.w, a3.x,a3.y,a3.z,a3.w,
                        a4.x,a4.y,a4.z,a4.w};
    float t[GC_HID];
#pragma unroll
    for (int j = 0; j < GC_HID; ++j) t[j] = bsh[j];
#pragma unroll
    for (int i = 0; i < GC_HID; ++i) {
        float x = h1[i];
#pragma unroll
        for (int j = 0; j < GC_HID; ++j) t[j] = fmaf(x, Wsh[i * GC_HID + j], t[j]);
    }
    float mx = -1e30f;
#pragma unroll
    for (int j = 0; j < GC_HID; ++j) { t[j] = fmaxf(t[j], 0.0f); mx = fmaxf(mx, t[j]); }
    float s = 0.0f;
#pragma unroll
    for (int j = 0; j < GC_HID; ++j) { t[j] = __expf(t[j] - mx); s += t[j]; }
    float inv = rs_s[node] / s;
#pragma unroll
    for (int j = 0; j < GC_HID; ++j) t[j] *= inv;
    float4* o = (float4*)&h2_pre[node * GC_HID];
    o[0] = make_float4(t[0],  t[1],  t[2],  t[3]);
    o[1] = make_float4(t[4],  t[5],  t[6],  t[7]);
    o[2] = make_float4(t[8],  t[9],  t[10], t[11]);
    o[3] = make_float4(t[12], t[13], t[14], t[15]);
    o[4] = make_float4(t[16], t[17], t[18], t[19]);
}

// fused encoder head, 4 waves/block (ENB=128, 782 blocks -> ~3 blocks/CU):
// wave = (half<<1)|node_group; half readfirstlane-scalarized -> s_load kept.
__global__ __launch_bounds__(256) void k_encf(const float* __restrict__ h2in,
                                              const float* __restrict__ nodes,
                                              const float* __restrict__ Wmu,
                                              const float* __restrict__ bmu,
                                              const float* __restrict__ Wls,
                                              const float* __restrict__ bls,
                                              float* __restrict__ mu_out,
                                              float* __restrict__ ls_out) {
    __shared__ float tile[ENB * 17];   // 8,704 B
    int t = threadIdx.x;
    int wave = t >> 6, lane = t & 63;
    int ng = wave & 1;                 // node group within block (0..1)
    int half = __builtin_amdgcn_readfirstlane(wave >> 1);  // 0 = mu, 1 = ls
    int n0 = blockIdx.x * ENB;
    int lrow = ng * 64 + lane;         // 0..127
    int node = n0 + lrow;
    const float* W  = half ? Wls : Wmu;
    const float* bb = half ? bls : bmu;
    float* out      = half ? ls_out : mu_out;

    float acc[Z_DIM];
#pragma unroll
    for (int j = 0; j < Z_DIM; ++j) acc[j] = bb[j];

    if (node < N_NODES) {
        const float4* hp = (const float4*)(h2in + (size_t)node * GC_HID);
#pragma unroll
        for (int v = 0; v < 5; ++v) {
            float4 hh = hp[v];
#pragma unroll
            for (int c = 0; c < 4; ++c) {
                float x = (c == 0) ? hh.x : (c == 1) ? hh.y : (c == 2) ? hh.z : hh.w;
                const float* wr = W + (v * 4 + c) * Z_DIM;
#pragma unroll
                for (int j = 0; j < Z_DIM; ++j) acc[j] = fmaf(x, wr[j], acc[j]);
            }
        }
    }
    // nodes contribution (K = 256, LDS-staged coalesced 16-float chunks)
    for (int ch = 0; ch < 16; ++ch) {
        __syncthreads();
#pragma unroll
        for (int rep = 0; rep < 2; ++rep) {
            int idx = rep * 256 + t;       // 0..511
            int row = idx >> 2, k4 = idx & 3;
            int gn = n0 + row;
            float4 v = (gn < N_NODES)
                ? ((const float4*)nodes)[(size_t)gn * 64 + ch * 4 + k4]
                : make_float4(0.f, 0.f, 0.f, 0.f);
            float* dst = &tile[row * 17 + k4 * 4];
            dst[0] = v.x; dst[1] = v.y; dst[2] = v.z; dst[3] = v.w;
        }
        __syncthreads();
#pragma unroll
        for (int kk = 0; kk < 16; ++kk) {
            float x = tile[lrow * 17 + kk];
            const float* wr = W + (GC_HID + ch * 16 + kk) * Z_DIM;
#pragma unroll
            for (int j = 0; j < Z_DIM; ++j) acc[j] = fmaf(x, wr[j], acc[j]);
        }
    }
    if (node >= N_NODES) return;
    float4* op = (float4*)(out + (size_t)node * Z_DIM);
#pragma unroll
    for (int v = 0; v < Z_DIM / 4; ++v)
        op[v] = make_float4(acc[4*v], acc[4*v+1], acc[4*v+2], acc[4*v+3]);
}

// reparameterization: z = mu + (1e-4 + exp(0.5*ls)) * eps
__global__ __launch_bounds__(256) void k_z(const float* __restrict__ mu,
                                           const float* __restrict__ ls,
                                           const float* __restrict__ eps,
                                           float* __restrict__ z) {
    int i = blockIdx.x * 256 + threadIdx.x;
    if (i >= N_NODES * Z_DIM / 4) return;
    float4 m = ((const float4*)mu)[i];
    float4 l = ((const float4*)ls)[i];
    float4 e = ((const float4*)eps)[i];
    float4 zz;
    zz.x = m.x + (1e-4f + __expf(0.5f * l.x)) * e.x;
    zz.y = m.y + (1e-4f + __expf(0.5f * l.y)) * e.y;
    zz.z = m.z + (1e-4f + __expf(0.5f * l.z)) * e.z;
    zz.w = m.w + (1e-4f + __expf(0.5f * l.w)) * e.w;
    ((float4*)z)[i] = zz;
}

// decoder stage 1: d = relu(z@Wd1+bd1), thread per node (weights uniform)
__global__ __launch_bounds__(256) void k_decd(const float* __restrict__ z,
                                              const float* __restrict__ Wd1,
                                              const float* __restrict__ bd1,
                                              float* __restrict__ dbuf) {
    int node = blockIdx.x * 256 + threadIdx.x;
    if (node >= N_NODES) return;
    float d[DEC_HID];
#pragma unroll
    for (int j = 0; j < DEC_HID; ++j) d[j] = bd1[j];
    const float4* zp = (const float4*)(z + (size_t)node * Z_DIM);
#pragma unroll
    for (int v = 0; v < Z_DIM / 4; ++v) {
        float4 zz = zp[v];
#pragma unroll
        for (int c = 0; c < 4; ++c) {
            float x = (c == 0) ? zz.x : (c == 1) ? zz.y : (c == 2) ? zz.z : zz.w;
            const float* wr = Wd1 + (v * 4 + c) * DEC_HID;
#pragma unroll
            for (int j = 0; j < DEC_HID; ++j) d[j] = fmaf(x, wr[j], d[j]);
        }
    }
    float4* op = (float4*)(dbuf + (size_t)node * DEC_HID);
#pragma unroll
    for (int v = 0; v < DEC_HID / 4; ++v)
        op[v] = make_float4(fmaxf(d[4*v], 0.f), fmaxf(d[4*v+1], 0.f),
                            fmaxf(d[4*v+2], 0.f), fmaxf(d[4*v+3], 0.f));
}

// decoder stage 2: chunk id forced wave-uniform via readfirstlane; lane = node.
__global__ __launch_bounds__(256) void k_decx(const float* __restrict__ dbuf,
                                              const float* __restrict__ Wd2,
                                              const float* __restrict__ bd2,
                                              float* __restrict__ X) {
    int lane = threadIdx.x & 63;
    int wv   = threadIdx.x >> 6;             // 0..3
    int ch   = __builtin_amdgcn_readfirstlane(((blockIdx.x & 1) << 2) | wv);
    int node = (blockIdx.x >> 1) * 64 + lane;
    if (node >= N_NODES) return;
    int co = ch << 5;
    float o[32];
#pragma unroll
    for (int j = 0; j < 32; ++j) o[j] = bd2[co + j];
    const float4* dp = (const float4*)(dbuf + (size_t)node * DEC_HID);
#pragma unroll
    for (int v = 0; v < DEC_HID / 4; ++v) {
        float4 dd = dp[v];
#pragma unroll
        for (int c = 0; c < 4; ++c) {
            float x = (c == 0) ? dd.x : (c == 1) ? dd.y : (c == 2) ? dd.z : dd.w;
            const float* wr = Wd2 + (v * 4 + c) * D_FEAT + co;
#pragma unroll
            for (int j = 0; j < 32; ++j) o[j] = fmaf(x, wr[j], o[j]);
        }
    }
    float4* xp = (float4*)(X + (size_t)node * D_FEAT + co);
#pragma unroll
    for (int v = 0; v < 8; ++v)
        xp[v] = make_float4(o[4*v], o[4*v+1], o[4*v+2], o[4*v+3]);
}

extern "C" void kernel_launch(void* const* d_in, const int* in_sizes, int n_in,
                              void* d_out, int out_size, void* d_ws, size_t ws_size,
                              hipStream_t stream) {
    const float* nodes = (const float*)d_in[0];
    const int*   snd   = (const int*)d_in[1];
    const int*   rcv   = (const int*)d_in[2];
    const float* eps   = (const float*)d_in[3];
    const float* W1    = (const float*)d_in[4];
    const float* b1    = (const float*)d_in[5];
    const float* W2    = (const float*)d_in[6];
    const float* b2    = (const float*)d_in[7];
    const float* Wmu   = (const float*)d_in[8];
    const float* bmu   = (const float*)d_in[9];
    const float* Wls   = (const float*)d_in[10];
    const float* bls   = (const float*)d_in[11];
    const float* Wd1   = (const float*)d_in[12];
    const float* bd1   = (const float*)d_in[13];
    const float* Wd2   = (const float*)d_in[14];
    const float* bd2   = (const float*)d_in[15];

    char* ws = (char*)d_ws;
    float*          h_pre    = (float*)(ws);
    float*          agg      = (float*)(ws + 8000000);
    float*          dbuf     = (float*)(ws);              // overlays h_pre+agg (dead)
    unsigned*       grec     = (unsigned*)(ws + 16000000);
    unsigned*       rec_r    = (unsigned*)(ws + 28804096);
    unsigned short* srow_r   = (unsigned short*)(ws + 41608192);
    unsigned*       pref_t   = (unsigned*)(ws + 42836720);
    float*          zbuf     = (float*)(ws + 28804096);   // reuses rec_r zone after gscat
    unsigned*       row_ptr  = (unsigned*)(ws + 45287504);
    unsigned*       gtot     = (unsigned*)(ws + 45687508);
    unsigned*       gbase    = (unsigned*)(ws + 45689076);
    float*          rs_s     = (float*)(ws + 45690648);
    unsigned char*  rec_s    = (unsigned char*)(ws + 46090648);
    unsigned short* srow_s   = (unsigned short*)(ws + 49291672);

    float* X      = (float*)d_out;
    float* mu_out = X + (size_t)N_NODES * D_FEAT;
    float* ls_out = mu_out + (size_t)N_NODES * Z_DIM;

    k_sort<<<NBLK, 512, 0, stream>>>(snd, rcv, rec_r, rec_s, srow_r, srow_s);
    k_degs<<<SB, 512, 0, stream>>>(rec_s, srow_s, rs_s);
    k_scanB<<<SB, 256, 0, stream>>>(srow_r, pref_t, gtot);
    k_scanG<<<1, 512, 0, stream>>>(gtot, gbase);
    k_gscat<<<NBLK, 256, 0, stream>>>(rec_r, srow_r, pref_t, gbase, grec);
    k_sort2<<<SB, 256, 0, stream>>>(grec, gbase, row_ptr);

    k_gc1<<<782, 128, 0, stream>>>(nodes, W1, b1, rs_s, h_pre);
    k_gather<<<1563, 320, 0, stream>>>(row_ptr, grec, h_pre, agg);
    k_gc2<<<391, 256, 0, stream>>>(agg, W2, b2, rs_s, h_pre);
    k_gather<<<1563, 320, 0, stream>>>(row_ptr, grec, h_pre, agg);

    k_encf<<<782, 256, 0, stream>>>(agg, nodes, Wmu, bmu, Wls, bls,
                                    mu_out, ls_out);
    k_z<<<3125, 256, 0, stream>>>(mu_out, ls_out, eps, zbuf);
    k_decd<<<391, 256, 0, stream>>>(zbuf, Wd1, bd1, dbuf);
    k_decx<<<3126, 256, 0, stream>>>(dbuf, Wd2, bd2, X);
}